// Round 6
// baseline (129604.993 us; speedup 1.0000x reference)
//
#include <hip/hip_runtime.h>
#include <hip/hip_bf16.h>
#include <math.h>

// Round 5 resubmit: Rounds 4 and 5 both failed with GPUAcquisitionTimeout
// (broker at capacity) — the persistent-recurrence kernel is still
// unmeasured. Identical source to Round 3's compile-fixed version.

#define B_   32
#define T_   2048
#define IN_  256
#define H_   512
#define O_   512

#define NSLICE     8                // column-split blocks per batch row
#define SLICE_COLS (H_ / NSLICE)    // 64 columns per block
#define KSLICES    16               // k-split within a block (one wave per k-slice)
#define KLEN       (H_ / KSLICES)   // 32 k-elements per thread

// ---------------------------------------------------------------------------
// Generic f32 GEMM with bias: C[M,N] = A[M,K] * Bm[K,N] + bias[N]
// (unchanged from Round 2; both GEMMs together measured ~1.06 ms)
// ---------------------------------------------------------------------------
__global__ __launch_bounds__(256) void gemm_bias_kernel(
    const float* __restrict__ A, const float* __restrict__ Bm,
    const float* __restrict__ bias, float* __restrict__ C,
    int M, int N, int K)
{
    constexpr int BK = 32;
    __shared__ float As[64][33];
    __shared__ float Bs[32][68];

    const int tid = threadIdx.x;
    const int tx  = tid & 15;
    const int ty  = tid >> 4;
    const int bn0 = blockIdx.x * 64;
    const int bm0 = blockIdx.y * 64;

    float acc[4][4] = {};

    for (int kk = 0; kk < K; kk += BK) {
        #pragma unroll
        for (int i = 0; i < 8; ++i) {
            int idx = tid + i * 256;
            int r = idx >> 5, k = idx & 31;
            As[r][k] = A[(size_t)(bm0 + r) * K + kk + k];
        }
        #pragma unroll
        for (int i = 0; i < 8; ++i) {
            int idx = tid + i * 256;
            int k = idx >> 6, c = idx & 63;
            Bs[k][c] = Bm[(size_t)(kk + k) * N + bn0 + c];
        }
        __syncthreads();

        #pragma unroll
        for (int k = 0; k < BK; ++k) {
            float a0 = As[ty * 4 + 0][k];
            float a1 = As[ty * 4 + 1][k];
            float a2 = As[ty * 4 + 2][k];
            float a3 = As[ty * 4 + 3][k];
            float4 b4 = *reinterpret_cast<const float4*>(&Bs[k][tx * 4]);
            acc[0][0] += a0 * b4.x; acc[0][1] += a0 * b4.y; acc[0][2] += a0 * b4.z; acc[0][3] += a0 * b4.w;
            acc[1][0] += a1 * b4.x; acc[1][1] += a1 * b4.y; acc[1][2] += a1 * b4.z; acc[1][3] += a1 * b4.w;
            acc[2][0] += a2 * b4.x; acc[2][1] += a2 * b4.y; acc[2][2] += a2 * b4.z; acc[2][3] += a2 * b4.w;
            acc[3][0] += a3 * b4.x; acc[3][1] += a3 * b4.y; acc[3][2] += a3 * b4.z; acc[3][3] += a3 * b4.w;
        }
        __syncthreads();
    }

    const float4 bv = *reinterpret_cast<const float4*>(&bias[bn0 + tx * 4]);
    #pragma unroll
    for (int i = 0; i < 4; ++i) {
        float4 o;
        o.x = acc[i][0] + bv.x;
        o.y = acc[i][1] + bv.y;
        o.z = acc[i][2] + bv.z;
        o.w = acc[i][3] + bv.w;
        *reinterpret_cast<float4*>(&C[(size_t)(bm0 + ty * 4 + i) * N + bn0 + tx * 4]) = o;
    }
}

// ---------------------------------------------------------------------------
// Persistent recurrence, W_hid fully VGPR-resident.
//   256 blocks x 1024 threads. Block (s,b) owns batch b, columns [s*64,s*64+64).
//   Thread (kg = tid>>6, j = tid&63) holds w[32] = W[kg*32..+32)[c0+j] in VGPRs.
//   Per step: h broadcast from LDS -> 32 FMA/thread -> LDS partial reduce ->
//   tanh -> exchange own 64-col slice with sibling blocks via d_ws (double-
//   buffered) + per-batch atomic counter.
//   Sibling blocks {b, b+32, ..., b+224} are congruent mod 8 -> same XCD
//   under round-robin dispatch (heuristic; correctness is placement-free).
//   Residency-safe without cooperative launch: 16 waves, <=128 VGPR, 6 KB LDS
//   => every CU hosts >=1 block => all 256 blocks resident under any packing.
// ---------------------------------------------------------------------------
__global__ __launch_bounds__(1024, 4) void rnn_recur_persist(
    const float* __restrict__ xp,   // [B,T,H] = x@W_in + b_hid
    const float* __restrict__ h0,   // [B,H]
    const float* __restrict__ Wh,   // [H,H] row-major
    float* __restrict__ hs,         // [B,T,H] output
    int* __restrict__ cnt,          // [B_ * 32] (128B-strided counters), zeroed
    float* __restrict__ hx)         // [2][B,H] exchange buffer
{
    __shared__ __align__(16) float h_lds[H_];
    __shared__ float part[KSLICES][SLICE_COLS];

    const int tid = threadIdx.x;
    const int b   = blockIdx.x & 31;   // batch row
    const int s   = blockIdx.x >> 5;   // column slice 0..7
    const int c0  = s * SLICE_COLS;
    const int j   = tid & 63;
    const int kg  = tid >> 6;          // 0..15 == wave index

    // Load resident W slice: w[kk] = Wh[(kg*32+kk)*512 + c0 + j]
    float w[KLEN];
    #pragma unroll
    for (int kk = 0; kk < KLEN; ++kk)
        w[kk] = Wh[(size_t)(kg * KLEN + kk) * H_ + c0 + j];

    const float* __restrict__ xpb = xp + (size_t)b * T_ * H_ + c0;
    float* __restrict__ hsb       = hs + (size_t)b * T_ * H_ + c0;
    int* cntb = cnt + b * 32;          // 128-byte stride: no false sharing

    float hv_out = 0.0f;               // previous step's h value (tid<64)

    for (int t = 0; t < T_; ++t) {
        // Issue xp load early — independent of the recurrence, hides under poll.
        float xpv = (tid < SLICE_COLS) ? xpb[(size_t)t * H_ + tid] : 0.0f;

        // Store PREVIOUS step's hs value now (off the exchange critical path).
        if (t > 0 && tid < SLICE_COLS)
            hsb[(size_t)(t - 1) * H_ + tid] = hv_out;

        // Wait for h_t to be fully published (all 8 sibling arrivals).
        if (tid == 0 && t > 0) {
            const int target = NSLICE * t;
            while (__hip_atomic_load(cntb, __ATOMIC_RELAXED,
                                     __HIP_MEMORY_SCOPE_AGENT) < target)
                __builtin_amdgcn_s_sleep(2);
            __builtin_amdgcn_fence(__ATOMIC_ACQUIRE, "agent");
        }
        __syncthreads();

        // Gather full h_t into LDS (slot parity = t&1).
        if (tid < H_) {
            float hv;
            if (t == 0) {
                hv = h0[b * H_ + tid];
            } else {
                hv = __hip_atomic_load(
                        &hx[((size_t)(t & 1) * B_ + b) * H_ + tid],
                        __ATOMIC_RELAXED, __HIP_MEMORY_SCOPE_AGENT);
            }
            h_lds[tid] = hv;
        }
        __syncthreads();

        // 32 FMA per thread against VGPR-resident weights; h is a wave-uniform
        // LDS broadcast (all lanes of wave kg read the same addresses).
        float acc = 0.0f;
        const float4* h4 = reinterpret_cast<const float4*>(&h_lds[kg * KLEN]);
        #pragma unroll
        for (int q = 0; q < KLEN / 4; ++q) {
            float4 hq = h4[q];
            acc += hq.x * w[4 * q + 0] + hq.y * w[4 * q + 1]
                 + hq.z * w[4 * q + 2] + hq.w * w[4 * q + 3];
        }
        part[kg][j] = acc;
        __syncthreads();

        // Reduce 16 partials, add xp, tanh, publish to exchange buffer.
        if (tid < SLICE_COLS) {
            float ssum = xpv;
            #pragma unroll
            for (int g = 0; g < KSLICES; ++g) ssum += part[g][tid];
            float hv = tanhf(ssum);
            hv_out = hv;
            __hip_atomic_store(
                &hx[((size_t)((t + 1) & 1) * B_ + b) * H_ + c0 + tid], hv,
                __ATOMIC_RELAXED, __HIP_MEMORY_SCOPE_AGENT);
        }
        // Drain own stores (writers), then block-wide order, then arrive.
        __threadfence();
        __syncthreads();
        if (tid == 0)
            __hip_atomic_fetch_add(cntb, 1, __ATOMIC_RELEASE,
                                   __HIP_MEMORY_SCOPE_AGENT);
    }
    // Final step's hs store.
    if (tid < SLICE_COLS)
        hsb[(size_t)(T_ - 1) * H_ + tid] = hv_out;
}

// ---------------------------------------------------------------------------
extern "C" void kernel_launch(void* const* d_in, const int* in_sizes, int n_in,
                              void* d_out, int out_size, void* d_ws, size_t ws_size,
                              hipStream_t stream)
{
    const float* x    = (const float*)d_in[0];  // [32,2048,256]
    const float* h0   = (const float*)d_in[1];  // [32,512]
    // d_in[2] = c : unused by the reference math
    const float* Win  = (const float*)d_in[3];  // [256,512]
    const float* Whid = (const float*)d_in[4];  // [512,512]
    const float* bhid = (const float*)d_in[5];  // [512]
    const float* Wout = (const float*)d_in[6];  // [512,512]
    const float* bout = (const float*)d_in[7];  // [512]

    float* hs    = (float*)d_out;                          // [32,2048,512]
    float* outs  = (float*)d_out + (size_t)B_ * T_ * H_;   // [32,2048,512]
    float* xproj = outs;  // staged in outs region, consumed before overwrite

    // d_ws layout: [0,4096) per-batch counters; [4096, 4096+128K) hx[2][32][512]
    int*   cnt = (int*)d_ws;
    float* hx  = (float*)((char*)d_ws + 4096);

    const int M = B_ * T_;            // 65536
    dim3 blk(256);
    dim3 grid_gemm(H_ / 64, M / 64);

    // Zero the sync counters (graph-capturable; runs on every replay).
    (void)hipMemsetAsync(d_ws, 0, 4096, stream);

    // 1) x_proj = x @ W_in + b_hid
    gemm_bias_kernel<<<grid_gemm, blk, 0, stream>>>(x, Win, bhid, xproj, M, H_, IN_);

    // 2) persistent recurrence -> hs
    rnn_recur_persist<<<dim3(NSLICE * B_), dim3(1024), 0, stream>>>(
        xproj, h0, Whid, hs, cnt, hx);

    // 3) outs = hs @ W_out + b_out (overwrites xproj)
    gemm_bias_kernel<<<grid_gemm, blk, 0, stream>>>(hs, Wout, bout, outs, M, O_, H_);
}